// Round 11
// baseline (235.235 us; speedup 1.0000x reference)
//
#include <hip/hip_runtime.h>
#include <math.h>

#define KSIZE 5
#define KTOT 125
#define CHUNK 2048

static constexpr float LOWER_CURV = -0.22703196f;
static constexpr float UPPER_CURV = 0.36853024f;

typedef _Float16 h2 __attribute__((ext_vector_type(2)));

__device__ __forceinline__ unsigned pack_u32(float a, float b) {
    return __builtin_bit_cast(unsigned, __builtin_amdgcn_cvt_pkrtz(a, b));
}
__device__ __forceinline__ float fdot2f(h2 a, h2 b, float c) {
#if __has_builtin(__builtin_amdgcn_fdot2)
    return __builtin_amdgcn_fdot2(a, b, c, false);
#else
    return c + (float)a[0] * (float)b[0] + (float)a[1] * (float)b[1];
#endif
}

__host__ __device__ static inline int cdiv(int a, int b) { return (a + b - 1) / b; }

// basis from 10-bit quantized fractions; bb[t] matches TAP[t]
__device__ __forceinline__ void unpack_bb10(unsigned w1, float bb[8]) {
    const float s = 1.0f / 1023.0f;
    float f0 = (float)(w1 & 1023u) * s;
    float f1 = (float)((w1 >> 10) & 1023u) * s;
    float f2 = (float)((w1 >> 20) & 1023u) * s;
    float a0 = 1.f - f0, a1 = 1.f - f1, a2 = 1.f - f2;
    float p00 = a0 * a1, p10 = f0 * a1, p01 = a0 * f1, p11 = f0 * f1;
    bb[0] = p00 * a2; bb[1] = p10 * a2; bb[2] = p01 * a2; bb[3] = p11 * a2;
    bb[4] = p00 * f2; bb[5] = p10 * f2; bb[6] = p01 * f2; bb[7] = p11 * f2;
}

__device__ __forceinline__ void spline_wf(const float* __restrict__ a3,
                                          int& wib, float fr[3]) {
    int k[3];
#pragma unroll
    for (int d = 0; d < 3; ++d) {
        float p = fminf(fmaxf(a3[d], 0.f), 1.f) * 4.f;
        float f0 = fminf(floorf(p), 3.f);
        k[d] = (int)f0;
        fr[d] = p - f0;
    }
    wib = k[0] * 25 + k[1] * 5 + k[2];
}

// ---------- preamble kernels ----------

// x transform + dst histogram + block-aggregated wib histogram (counts/bcnt pre-zeroed)
__global__ __launch_bounds__(256) void hist_tr(
        const float* __restrict__ x, float* __restrict__ h,
        const int* __restrict__ dst, const float* __restrict__ attr,
        int* __restrict__ counts, int* __restrict__ bcnt, int N, int E) {
    __shared__ int lh[KTOT];
    const int tid = threadIdx.x;
    for (int i = tid; i < KTOT; i += 256) lh[i] = 0;
    __syncthreads();
    int i = blockIdx.x * 256 + tid;
    if (i < N) {
        float t = (x[i] - LOWER_CURV) / (UPPER_CURV - LOWER_CURV) * 20.0f - 10.0f;
        h[i] = fminf(fmaxf(t, -10.0f), 10.0f);
    }
    const int base = blockIdx.x * CHUNK;
#pragma unroll
    for (int k = 0; k < 8; ++k) {
        int e = base + tid + k * 256;
        if (e < E) {
            atomicAdd(&counts[dst[e]], 1);
            float a3[3] = {attr[e * 3], attr[e * 3 + 1], attr[e * 3 + 2]};
            int wib; float fr[3];
            spline_wf(a3, wib, fr);
            atomicAdd(&lh[wib], 1);
        }
    }
    __syncthreads();
    for (int j = tid; j < KTOT; j += 256) {
        int c = lh[j];
        if (c) atomicAdd(&bcnt[j], c);
    }
}

__global__ void scan_blocks(const int* __restrict__ counts, int* __restrict__ rowptr,
                            int* __restrict__ bsums, int n) {
    __shared__ int sh[256];
    int tid = threadIdx.x;
    int i = blockIdx.x * 256 + tid;
    int v = (i < n) ? counts[i] : 0;
    sh[tid] = v;
    __syncthreads();
    for (int off = 1; off < 256; off <<= 1) {
        int t = (tid >= off) ? sh[tid - off] : 0;
        __syncthreads();
        sh[tid] += t;
        __syncthreads();
    }
    if (i < n) rowptr[i] = sh[tid] - v;
    if (tid == 255) bsums[blockIdx.x] = sh[255];
}

// rowptr offset + cursor init; block 0 additionally scans the 125 bucket counts
__global__ void add_offsets2(int* __restrict__ rowptr, const int* __restrict__ bsums,
                             int* __restrict__ cursor, const int* __restrict__ bcnt,
                             int* __restrict__ bcursor, int nb, int n, int E) {
    __shared__ int sh[256];
    __shared__ int sb[128];
    int tid = threadIdx.x;
    int v = (tid < nb) ? bsums[tid] : 0;
    sh[tid] = v;
    __syncthreads();
    for (int off = 1; off < 256; off <<= 1) {
        int t = (tid >= off) ? sh[tid - off] : 0;
        __syncthreads();
        sh[tid] += t;
        __syncthreads();
    }
    int boff = (blockIdx.x == 0) ? 0 : sh[blockIdx.x - 1];
    int i = blockIdx.x * 256 + tid;
    if (i < n) {
        int r = rowptr[i] + boff;
        rowptr[i] = r;
        cursor[i] = r;
    }
    if (i == 0) rowptr[n] = E;
    if (blockIdx.x == 0) {
        int b0 = 0;
        if (tid < 128) {
            b0 = (tid < KTOT) ? bcnt[tid] : 0;
            sb[tid] = b0;
        }
        __syncthreads();
        for (int off = 1; off < 128; off <<= 1) {
            int t = (tid >= off && tid < 128) ? sb[tid - off] : 0;
            __syncthreads();
            if (tid < 128) sb[tid] += t;
            __syncthreads();
        }
        if (tid < KTOT) bcursor[tid] = sb[tid] - b0;
    }
}

// GLOBAL bucket sort by wib via block-aggregated reserve (blocks < nchunk)
// + f16 weight-table prep (tail blocks).
// Records 8B: w0 = src | wib<<18; w1 = q0|q1<<10|q2<<20.
__global__ __launch_bounds__(256) void scatter_prep(
        const int* __restrict__ src, const int* __restrict__ dst,
        const float* __restrict__ attr, int* __restrict__ cursor,
        int* __restrict__ bcursor,
        uint2* __restrict__ records, uint2* __restrict__ records_d,
        int* __restrict__ iperm, int E, int nchunk,
        const float* __restrict__ W2, const float* __restrict__ W3,
        const float* __restrict__ W4, _Float16* __restrict__ wh2,
        _Float16* __restrict__ wh3, _Float16* __restrict__ wh4) {
    __shared__ int lh[KTOT], lbase[KTOT], lrank[KTOT];
    const int tid = threadIdx.x;

    if ((int)blockIdx.x >= nchunk) {
        // ---- weight prep: Wh[wi][(i>>3)][o][i&7] = W[wi][i][o] ----
        int idx = ((int)blockIdx.x - nchunk) * 256 + tid;   // < 64000
        const float* W; _Float16* Wh; int Cin, Cout, r;
        if (idx < 16000)      { W = W2; Wh = wh2; Cin = 8;  Cout = 16; r = idx; }
        else if (idx < 48000) { W = W3; Wh = wh3; Cin = 16; Cout = 16; r = idx - 16000; }
        else                  { W = W4; Wh = wh4; Cin = 16; Cout = 8;  r = idx - 48000; }
        int wi = r / (Cin * Cout);
        int q = r % (Cin * Cout);
        int i = q / Cout, o = q % Cout;
        Wh[wi * (Cin * Cout) + (i >> 3) * (8 * Cout) + o * 8 + (i & 7)] = (_Float16)W[r];
        return;
    }

    for (int i = tid; i < KTOT; i += 256) { lh[i] = 0; lrank[i] = 0; }
    __syncthreads();
    const int base = blockIdx.x * CHUNK;

    int wibs[8]; unsigned w1s[8];
#pragma unroll
    for (int k = 0; k < 8; ++k) {
        int e = base + tid + k * 256;
        wibs[k] = -1;
        if (e < E) {
            float a3[3] = {attr[e * 3], attr[e * 3 + 1], attr[e * 3 + 2]};
            int wib; float fr[3];
            spline_wf(a3, wib, fr);
            wibs[k] = wib;
            unsigned q0 = (unsigned)__float2int_rn(fr[0] * 1023.f);
            unsigned q1 = (unsigned)__float2int_rn(fr[1] * 1023.f);
            unsigned q2 = (unsigned)__float2int_rn(fr[2] * 1023.f);
            w1s[k] = q0 | (q1 << 10) | (q2 << 20);
            atomicAdd(&lh[wib], 1);
        }
    }
    __syncthreads();
    for (int i = tid; i < KTOT; i += 256) {
        int c = lh[i];
        lbase[i] = c ? atomicAdd(&bcursor[i], c) : 0;
    }
    __syncthreads();
#pragma unroll
    for (int k = 0; k < 8; ++k) {
        int e = base + tid + k * 256;
        if (e < E) {
            int w = wibs[k];
            int pos = lbase[w] + atomicAdd(&lrank[w], 1);
            uint2 rec = make_uint2((unsigned)src[e] | ((unsigned)w << 18), w1s[k]);
            records[pos] = rec;
            int p = atomicAdd(&cursor[dst[e]], 1);
            iperm[pos] = p;
            records_d[p] = rec;
        }
    }
}

// ---------- phase A: edge GEMM over globally sorted records ----------
// Contiguous span per wave; per-lane weight columns register-cached across
// uniform-wib runs (LDS fallback at bucket boundaries).
template<int Cin, int Cout>
__global__ __launch_bounds__(512) void edge_gemm(
        const uint2* __restrict__ records, const unsigned* __restrict__ xh,
        const _Float16* __restrict__ Wg, const int* __restrict__ iperm,
        _Float16* __restrict__ y, int E) {
    constexpr int SLOTS = 64 / Cout;
    constexpr int CC = Cin * Cout;
    constexpr int WH = KTOT * CC;
    constexpr int NW = 512 * 8;
    __shared__ __align__(16) _Float16 Wl[WH];
    for (int t = threadIdx.x; t < WH / 8; t += 512)
        ((uint4*)Wl)[t] = ((const uint4*)Wg)[t];
    __syncthreads();

    const int lane = threadIdx.x & 63;
    const int o = lane & (Cout - 1);
    const int slot = lane / Cout;
    const int wid = blockIdx.x * 8 + (threadIdx.x >> 6);

    int span = cdiv(cdiv(E, NW), SLOTS) * SLOTS;
    int begin = wid * span;
    int endv = begin + span;
    if (endv > E) endv = E;
    if (begin >= E) return;

    constexpr int TAP[8] = {0, 25, 5, 30, 1, 26, 6, 31};

    unsigned cached = 0xFFFFFFFFu;
    h2 wreg[8][Cin / 2];

    for (int base = begin; base < endv; base += SLOTS) {
        const int idx = base + slot;
        const bool act = idx < endv;
        const int ridx = act ? idx : endv - 1;
        uint2 rec = records[ridx];
        float bb[8];
        unpack_bb10(rec.y, bb);
        const unsigned wib = rec.x >> 18;
        const unsigned sn = rec.x & 0x3FFFFu;

        h2 hx[Cin / 2];
        const uint4* xp = (const uint4*)(xh + (size_t)sn * (Cin / 2));
#pragma unroll
        for (int c = 0; c < Cin / 8; ++c) {
            uint4 q = xp[c];
            hx[4 * c + 0] = __builtin_bit_cast(h2, q.x);
            hx[4 * c + 1] = __builtin_bit_cast(h2, q.y);
            hx[4 * c + 2] = __builtin_bit_cast(h2, q.z);
            hx[4 * c + 3] = __builtin_bit_cast(h2, q.w);
        }

        unsigned w0 = (unsigned)__builtin_amdgcn_readfirstlane((int)wib);
        float acc = 0.f;
        if (__all((int)(wib == w0))) {
            if (w0 != cached) {
                cached = w0;
#pragma unroll
                for (int t = 0; t < 8; ++t) {
                    const _Float16* wp = &Wl[(w0 + TAP[t]) * CC + o * 8];
#pragma unroll
                    for (int c = 0; c < Cin / 8; ++c) {
                        union { uint4 u4; unsigned u[4]; } wu;
                        wu.u4 = *(const uint4*)(wp + c * (8 * Cout));
                        wreg[t][4 * c + 0] = __builtin_bit_cast(h2, wu.u[0]);
                        wreg[t][4 * c + 1] = __builtin_bit_cast(h2, wu.u[1]);
                        wreg[t][4 * c + 2] = __builtin_bit_cast(h2, wu.u[2]);
                        wreg[t][4 * c + 3] = __builtin_bit_cast(h2, wu.u[3]);
                    }
                }
            }
#pragma unroll
            for (int t = 0; t < 8; ++t) {
                float dot = 0.f;
#pragma unroll
                for (int k = 0; k < Cin / 2; ++k)
                    dot = fdot2f(hx[k], wreg[t][k], dot);
                acc = fmaf(bb[t], dot, acc);
            }
        } else {
            cached = 0xFFFFFFFFu;
#pragma unroll
            for (int t = 0; t < 8; ++t) {
                const _Float16* wp = &Wl[(wib + TAP[t]) * CC + o * 8];
                float dot = 0.f;
#pragma unroll
                for (int c = 0; c < Cin / 8; ++c) {
                    union { uint4 u4; unsigned u[4]; } wu;
                    wu.u4 = *(const uint4*)(wp + c * (8 * Cout));
                    dot = fdot2f(hx[4 * c + 0], __builtin_bit_cast(h2, wu.u[0]), dot);
                    dot = fdot2f(hx[4 * c + 1], __builtin_bit_cast(h2, wu.u[1]), dot);
                    dot = fdot2f(hx[4 * c + 2], __builtin_bit_cast(h2, wu.u[2]), dot);
                    dot = fdot2f(hx[4 * c + 3], __builtin_bit_cast(h2, wu.u[3]), dot);
                }
                acc = fmaf(bb[t], dot, acc);
            }
        }
        if (act) {
            int dpos = iperm[idx];
            y[(size_t)dpos * Cout + o] = (_Float16)acc;
        }
    }
}

// ---------- phase B: sequential y reduce + root + ELU; writes f32 + packed f16 ----------
template<int Cin, int Cout>
__global__ void node_reduce(const int* __restrict__ rowptr,
                            const unsigned* __restrict__ yu,
                            const float* __restrict__ x,
                            const float* __restrict__ root,
                            const float* __restrict__ bias,
                            float* __restrict__ out, unsigned* __restrict__ xh,
                            int N) {
    constexpr int C2 = Cout / 2;
    int t = blockIdx.x * blockDim.x + threadIdx.x;
    int v = t / C2, o2 = t % C2;
    if (v >= N) return;
    int beg = rowptr[v], end = rowptr[v + 1];
    float a0 = 0.f, a1 = 0.f;
    for (int p = beg; p < end; ++p) {
        h2 hh = __builtin_bit_cast(h2, yu[(size_t)p * C2 + o2]);
        a0 += (float)hh[0];
        a1 += (float)hh[1];
    }
    const int o = 2 * o2;
    a0 += bias[o]; a1 += bias[o + 1];
#pragma unroll
    for (int i = 0; i < Cin; ++i) {
        float xv = x[(size_t)v * Cin + i];
        a0 = fmaf(xv, root[i * Cout + o], a0);
        a1 = fmaf(xv, root[i * Cout + o + 1], a1);
    }
    a0 = a0 > 0.f ? a0 : expm1f(a0);
    a1 = a1 > 0.f ? a1 : expm1f(a1);
    ((float2*)out)[(size_t)v * C2 + o2] = make_float2(a0, a1);
    xh[(size_t)v * C2 + o2] = pack_u32(a0, a1);
}

// ---------- fused small layers (records_d in dst-CSR order: contiguous reads) ----------

__global__ __launch_bounds__(512) void agg_l1(
        const int* __restrict__ rowptr, const uint2* __restrict__ records_d,
        const float* __restrict__ x, const float* __restrict__ W,
        const float* __restrict__ root, const float* __restrict__ bias,
        float* __restrict__ out, unsigned* __restrict__ xh2,
        int N, int totalWaves) {
    const int lane = threadIdx.x & 63;
    const int o = lane & 7;
    const int slot = lane >> 3;
    const int wid = blockIdx.x * 8 + (threadIdx.x >> 6);
    constexpr int TAP[8] = {0, 25, 5, 30, 1, 26, 6, 31};

    for (int v = wid; v < N; v += totalWaves) {
        const int beg = rowptr[v], end = rowptr[v + 1];
        float acc = 0.0f;
        for (int p0 = beg; p0 < end; p0 += 8) {
            const int p = p0 + slot;
            float xv = 0.f, bb[8];
            int wib = 0;
#pragma unroll
            for (int t = 0; t < 8; ++t) bb[t] = 0.f;
            if (p < end) {
                uint2 rec = records_d[p];
                unpack_bb10(rec.y, bb);
                wib = (int)(rec.x >> 18);
                xv = x[rec.x & 0x3FFFFu];
            }
#pragma unroll
            for (int t = 0; t < 8; ++t)
                acc = fmaf(bb[t] * xv, __ldg(&W[(wib + TAP[t]) * 8 + o]), acc);
        }
#pragma unroll
        for (int m = 8; m < 64; m <<= 1) acc += __shfl_xor(acc, m);
        if (slot == 0) {
            float z = acc + bias[o] + x[v] * root[o];
            z = z > 0.0f ? z : expm1f(z);
            out[(size_t)v * 8 + o] = z;
            float zp = __shfl_xor(z, 1);
            if ((o & 1) == 0) xh2[(size_t)v * 4 + (o >> 1)] = pack_u32(z, zp);
        }
    }
}

__global__ __launch_bounds__(512) void agg_l5(
        const int* __restrict__ rowptr, const uint2* __restrict__ records_d,
        const float* __restrict__ x, const float* __restrict__ W,
        const float* __restrict__ root, const float* __restrict__ bias,
        float* __restrict__ out, int N, int totalWaves) {
    const int lane = threadIdx.x & 63;
    const int i = lane & 7;
    const int slot = lane >> 3;
    const int wid = blockIdx.x * 8 + (threadIdx.x >> 6);
    constexpr int TAP[8] = {0, 25, 5, 30, 1, 26, 6, 31};

    for (int v = wid; v < N; v += totalWaves) {
        const int beg = rowptr[v], end = rowptr[v + 1];
        float acc = 0.0f;
        for (int p0 = beg; p0 < end; p0 += 8) {
            const int p = p0 + slot;
            float xi = 0.f, bb[8];
            int wib = 0;
#pragma unroll
            for (int t = 0; t < 8; ++t) bb[t] = 0.f;
            if (p < end) {
                uint2 rec = records_d[p];
                unpack_bb10(rec.y, bb);
                wib = (int)(rec.x >> 18);
                xi = x[(size_t)(rec.x & 0x3FFFFu) * 8 + i];
            }
#pragma unroll
            for (int t = 0; t < 8; ++t)
                acc = fmaf(bb[t] * xi, __ldg(&W[(wib + TAP[t]) * 8 + i]), acc);
        }
        if (slot == 0) acc = fmaf(x[(size_t)v * 8 + i], root[i], acc);
#pragma unroll
        for (int m = 1; m < 64; m <<= 1) acc += __shfl_xor(acc, m);
        if (lane == 0) {
            float z = acc + bias[0];
            out[v] = z > 0.0f ? z : expm1f(z);
        }
    }
}

// ---------- host ----------

static inline char* align256(char* p) {
    return (char*)(((uintptr_t)p + 255) & ~(uintptr_t)255);
}

extern "C" void kernel_launch(void* const* d_in, const int* in_sizes, int n_in,
                              void* d_out, int out_size, void* d_ws, size_t ws_size,
                              hipStream_t stream) {
    const float* x    = (const float*)d_in[0];
    const int*   ei   = (const int*)d_in[1];
    const float* attr = (const float*)d_in[2];
    const float* w[5]    = {(const float*)d_in[3],  (const float*)d_in[6],
                            (const float*)d_in[9],  (const float*)d_in[12],
                            (const float*)d_in[15]};
    const float* root[5] = {(const float*)d_in[4],  (const float*)d_in[7],
                            (const float*)d_in[10], (const float*)d_in[13],
                            (const float*)d_in[16]};
    const float* bias[5] = {(const float*)d_in[5],  (const float*)d_in[8],
                            (const float*)d_in[11], (const float*)d_in[14],
                            (const float*)d_in[17]};

    const int N = in_sizes[0];
    const int E = in_sizes[1] / 2;
    const int* src = ei;
    const int* dst = ei + E;

    char* ws = (char*)d_ws;
    float* bufA      = (float*)ws;    ws = align256(ws + (size_t)N * 16 * 4);
    float* bufB      = (float*)ws;    ws = align256(ws + (size_t)N * 16 * 4);
    int*   counts    = (int*)ws;      ws = align256(ws + (size_t)(N + 128) * 4);
    int*   bcnt      = counts + N;    // zeroed together with counts
    int*   cursor    = (int*)ws;      ws = align256(ws + (size_t)N * 4);
    int*   rowptr    = (int*)ws;      ws = align256(ws + (size_t)(N + 1) * 4);
    int*   bsums     = (int*)ws;      ws = align256(ws + 256 * 4);
    int*   bcursor   = (int*)ws;      ws = align256(ws + 128 * 4);
    uint2* records   = (uint2*)ws;    ws = align256(ws + (size_t)E * 8);
    uint2* records_d = (uint2*)ws;    ws = align256(ws + (size_t)E * 8);
    int*   iperm     = (int*)ws;      ws = align256(ws + (size_t)E * 4);
    _Float16* y      = (_Float16*)ws; ws = align256(ws + (size_t)E * 16 * 2);
    unsigned* xhA    = (unsigned*)ws; ws = align256(ws + (size_t)N * 8 * 4);
    unsigned* xhB    = (unsigned*)ws; ws = align256(ws + (size_t)N * 8 * 4);
    _Float16* wh2    = (_Float16*)ws; ws = align256(ws + (size_t)KTOT * 8 * 16 * 2);
    _Float16* wh3    = (_Float16*)ws; ws = align256(ws + (size_t)KTOT * 16 * 16 * 2);
    _Float16* wh4    = (_Float16*)ws; ws = align256(ws + (size_t)KTOT * 16 * 8 * 2);

    const int B = 256;
    const int nb = cdiv(N, 256);
    const int nchunk = cdiv(E, CHUNK);
    const int nprep = cdiv(64000, 256);
    const unsigned* yu = (const unsigned*)y;

    (void)hipMemsetAsync(counts, 0, (size_t)(N + 128) * 4, stream);
    hist_tr<<<nchunk, 256, 0, stream>>>(x, bufA, dst, attr, counts, bcnt, N, E);
    scan_blocks<<<nb, 256, 0, stream>>>(counts, rowptr, bsums, N);
    add_offsets2<<<nb, 256, 0, stream>>>(rowptr, bsums, cursor, bcnt, bcursor,
                                         nb, N, E);
    scatter_prep<<<nchunk + nprep, 256, 0, stream>>>(
        src, dst, attr, cursor, bcursor, records, records_d, iperm, E, nchunk,
        w[1], w[2], w[3], wh2, wh3, wh4);

    const int GB = 512, TW = GB * 8;

    // L1 (1->8), fused; writes f32 out + f16 xhA
    agg_l1<<<GB, 512, 0, stream>>>(rowptr, records_d, bufA, w[0],
                                   root[0], bias[0], bufB, xhA, N, TW);
    // L2 (8->16)
    edge_gemm<8, 16><<<512, 512, 0, stream>>>(records, xhA, wh2, iperm, y, E);
    node_reduce<8, 16><<<cdiv(N * 8, B), B, 0, stream>>>(rowptr, yu, bufB,
                                                         root[1], bias[1], bufA, xhB, N);
    // L3 (16->16)
    edge_gemm<16, 16><<<512, 512, 0, stream>>>(records, xhB, wh3, iperm, y, E);
    node_reduce<16, 16><<<cdiv(N * 8, B), B, 0, stream>>>(rowptr, yu, bufA,
                                                          root[2], bias[2], bufB, xhA, N);
    // L4 (16->8)
    edge_gemm<16, 8><<<512, 512, 0, stream>>>(records, xhA, wh4, iperm, y, E);
    node_reduce<16, 8><<<cdiv(N * 4, B), B, 0, stream>>>(rowptr, yu, bufB,
                                                         root[3], bias[3], bufA, xhB, N);
    // L5 (8->1), fused
    agg_l5<<<GB, 512, 0, stream>>>(rowptr, records_d, bufA, w[4],
                                   root[4], bias[4], (float*)d_out, N, TW);
}

// Round 12
// 220.967 us; speedup vs baseline: 1.0646x; 1.0646x over previous
//
#include <hip/hip_runtime.h>
#include <math.h>

#define KSIZE 5
#define KTOT 125
#define CHUNK 2048

static constexpr float LOWER_CURV = -0.22703196f;
static constexpr float UPPER_CURV = 0.36853024f;

typedef _Float16 h2 __attribute__((ext_vector_type(2)));

__device__ __forceinline__ unsigned pack_u32(float a, float b) {
    return __builtin_bit_cast(unsigned, __builtin_amdgcn_cvt_pkrtz(a, b));
}
__device__ __forceinline__ float fdot2f(h2 a, h2 b, float c) {
#if __has_builtin(__builtin_amdgcn_fdot2)
    return __builtin_amdgcn_fdot2(a, b, c, false);
#else
    return c + (float)a[0] * (float)b[0] + (float)a[1] * (float)b[1];
#endif
}

__host__ __device__ static inline int cdiv(int a, int b) { return (a + b - 1) / b; }

// basis from 10-bit quantized fractions; bb[t] matches TAP[t]
__device__ __forceinline__ void unpack_bb10(unsigned w1, float bb[8]) {
    const float s = 1.0f / 1023.0f;
    float f0 = (float)(w1 & 1023u) * s;
    float f1 = (float)((w1 >> 10) & 1023u) * s;
    float f2 = (float)((w1 >> 20) & 1023u) * s;
    float a0 = 1.f - f0, a1 = 1.f - f1, a2 = 1.f - f2;
    float p00 = a0 * a1, p10 = f0 * a1, p01 = a0 * f1, p11 = f0 * f1;
    bb[0] = p00 * a2; bb[1] = p10 * a2; bb[2] = p01 * a2; bb[3] = p11 * a2;
    bb[4] = p00 * f2; bb[5] = p10 * f2; bb[6] = p01 * f2; bb[7] = p11 * f2;
}

__device__ __forceinline__ void spline_wf(const float* __restrict__ a3,
                                          int& wib, float fr[3]) {
    int k[3];
#pragma unroll
    for (int d = 0; d < 3; ++d) {
        float p = fminf(fmaxf(a3[d], 0.f), 1.f) * 4.f;
        float f0 = fminf(floorf(p), 3.f);
        k[d] = (int)f0;
        fr[d] = p - f0;
    }
    wib = k[0] * 25 + k[1] * 5 + k[2];
}

// ---------- preamble kernels ----------

// x transform + dst histogram + block-aggregated wib histogram (counts/bcnt pre-zeroed)
__global__ __launch_bounds__(256) void hist_tr(
        const float* __restrict__ x, float* __restrict__ h,
        const int* __restrict__ dst, const float* __restrict__ attr,
        int* __restrict__ counts, int* __restrict__ bcnt, int N, int E) {
    __shared__ int lh[KTOT];
    const int tid = threadIdx.x;
    for (int i = tid; i < KTOT; i += 256) lh[i] = 0;
    __syncthreads();
    int i = blockIdx.x * 256 + tid;
    if (i < N) {
        float t = (x[i] - LOWER_CURV) / (UPPER_CURV - LOWER_CURV) * 20.0f - 10.0f;
        h[i] = fminf(fmaxf(t, -10.0f), 10.0f);
    }
    const int base = blockIdx.x * CHUNK;
#pragma unroll
    for (int k = 0; k < 8; ++k) {
        int e = base + tid + k * 256;
        if (e < E) {
            atomicAdd(&counts[dst[e]], 1);
            float a3[3] = {attr[e * 3], attr[e * 3 + 1], attr[e * 3 + 2]};
            int wib; float fr[3];
            spline_wf(a3, wib, fr);
            atomicAdd(&lh[wib], 1);
        }
    }
    __syncthreads();
    for (int j = tid; j < KTOT; j += 256) {
        int c = lh[j];
        if (c) atomicAdd(&bcnt[j], c);
    }
}

__global__ void scan_blocks(const int* __restrict__ counts, int* __restrict__ rowptr,
                            int* __restrict__ bsums, int n) {
    __shared__ int sh[256];
    int tid = threadIdx.x;
    int i = blockIdx.x * 256 + tid;
    int v = (i < n) ? counts[i] : 0;
    sh[tid] = v;
    __syncthreads();
    for (int off = 1; off < 256; off <<= 1) {
        int t = (tid >= off) ? sh[tid - off] : 0;
        __syncthreads();
        sh[tid] += t;
        __syncthreads();
    }
    if (i < n) rowptr[i] = sh[tid] - v;
    if (tid == 255) bsums[blockIdx.x] = sh[255];
}

// rowptr offset + cursor init; block 0 additionally scans the 125 bucket counts
__global__ void add_offsets2(int* __restrict__ rowptr, const int* __restrict__ bsums,
                             int* __restrict__ cursor, const int* __restrict__ bcnt,
                             int* __restrict__ bcursor, int nb, int n, int E) {
    __shared__ int sh[256];
    __shared__ int sb[128];
    int tid = threadIdx.x;
    int v = (tid < nb) ? bsums[tid] : 0;
    sh[tid] = v;
    __syncthreads();
    for (int off = 1; off < 256; off <<= 1) {
        int t = (tid >= off) ? sh[tid - off] : 0;
        __syncthreads();
        sh[tid] += t;
        __syncthreads();
    }
    int boff = (blockIdx.x == 0) ? 0 : sh[blockIdx.x - 1];
    int i = blockIdx.x * 256 + tid;
    if (i < n) {
        int r = rowptr[i] + boff;
        rowptr[i] = r;
        cursor[i] = r;
    }
    if (i == 0) rowptr[n] = E;
    if (blockIdx.x == 0) {
        int b0 = 0;
        if (tid < 128) {
            b0 = (tid < KTOT) ? bcnt[tid] : 0;
            sb[tid] = b0;
        }
        __syncthreads();
        for (int off = 1; off < 128; off <<= 1) {
            int t = (tid >= off && tid < 128) ? sb[tid - off] : 0;
            __syncthreads();
            if (tid < 128) sb[tid] += t;
            __syncthreads();
        }
        if (tid < KTOT) bcursor[tid] = sb[tid] - b0;
    }
}

// GLOBAL bucket sort by wib via block-aggregated reserve (blocks < nchunk)
// + f16 weight-table prep (tail blocks).
// Records 8B: w0 = src | wib<<18; w1 = q0|q1<<10|q2<<20.
__global__ __launch_bounds__(256) void scatter_prep(
        const int* __restrict__ src, const int* __restrict__ dst,
        const float* __restrict__ attr, int* __restrict__ cursor,
        int* __restrict__ bcursor,
        uint2* __restrict__ records, uint2* __restrict__ records_d,
        int* __restrict__ iperm, int E, int nchunk,
        const float* __restrict__ W2, const float* __restrict__ W3,
        const float* __restrict__ W4, _Float16* __restrict__ wh2,
        _Float16* __restrict__ wh3, _Float16* __restrict__ wh4) {
    __shared__ int lh[KTOT], lbase[KTOT], lrank[KTOT];
    const int tid = threadIdx.x;

    if ((int)blockIdx.x >= nchunk) {
        // ---- weight prep: Wh[wi][(i>>3)][o][i&7] = W[wi][i][o] ----
        int idx = ((int)blockIdx.x - nchunk) * 256 + tid;   // < 64000
        const float* W; _Float16* Wh; int Cin, Cout, r;
        if (idx < 16000)      { W = W2; Wh = wh2; Cin = 8;  Cout = 16; r = idx; }
        else if (idx < 48000) { W = W3; Wh = wh3; Cin = 16; Cout = 16; r = idx - 16000; }
        else                  { W = W4; Wh = wh4; Cin = 16; Cout = 8;  r = idx - 48000; }
        int wi = r / (Cin * Cout);
        int q = r % (Cin * Cout);
        int i = q / Cout, o = q % Cout;
        Wh[wi * (Cin * Cout) + (i >> 3) * (8 * Cout) + o * 8 + (i & 7)] = (_Float16)W[r];
        return;
    }

    for (int i = tid; i < KTOT; i += 256) { lh[i] = 0; lrank[i] = 0; }
    __syncthreads();
    const int base = blockIdx.x * CHUNK;

    int wibs[8]; unsigned w1s[8];
#pragma unroll
    for (int k = 0; k < 8; ++k) {
        int e = base + tid + k * 256;
        wibs[k] = -1;
        if (e < E) {
            float a3[3] = {attr[e * 3], attr[e * 3 + 1], attr[e * 3 + 2]};
            int wib; float fr[3];
            spline_wf(a3, wib, fr);
            wibs[k] = wib;
            unsigned q0 = (unsigned)__float2int_rn(fr[0] * 1023.f);
            unsigned q1 = (unsigned)__float2int_rn(fr[1] * 1023.f);
            unsigned q2 = (unsigned)__float2int_rn(fr[2] * 1023.f);
            w1s[k] = q0 | (q1 << 10) | (q2 << 20);
            atomicAdd(&lh[wib], 1);
        }
    }
    __syncthreads();
    for (int i = tid; i < KTOT; i += 256) {
        int c = lh[i];
        lbase[i] = c ? atomicAdd(&bcursor[i], c) : 0;
    }
    __syncthreads();
#pragma unroll
    for (int k = 0; k < 8; ++k) {
        int e = base + tid + k * 256;
        if (e < E) {
            int w = wibs[k];
            int pos = lbase[w] + atomicAdd(&lrank[w], 1);
            uint2 rec = make_uint2((unsigned)src[e] | ((unsigned)w << 18), w1s[k]);
            records[pos] = rec;
            int p = atomicAdd(&cursor[dst[e]], 1);
            iperm[pos] = p;
            records_d[p] = rec;
        }
    }
}

// ---------- phase A: edge GEMM over globally sorted records ----------
// Run loop: weights for the current wib loaded into registers UNCONDITIONALLY
// before the inner window loop (structurally loop-invariant). No LDS at all:
// weights come from L2/L1 once per run. Run boundary via ballot/ffs.
template<int Cin, int Cout>
__global__ __launch_bounds__(512) void edge_gemm(
        const uint2* __restrict__ records, const unsigned* __restrict__ xh,
        const _Float16* __restrict__ Wg, const int* __restrict__ iperm,
        _Float16* __restrict__ y, int E) {
    constexpr int SLOTS = 64 / Cout;
    constexpr int CC = Cin * Cout;
    constexpr int LOG2C = (Cout == 16) ? 4 : 3;
    const int lane = threadIdx.x & 63;
    const int o = lane & (Cout - 1);
    const int slot = lane / Cout;
    const int nwaves = gridDim.x * 8;
    const int wid = blockIdx.x * 8 + (threadIdx.x >> 6);
    constexpr int TAP[8] = {0, 25, 5, 30, 1, 26, 6, 31};

    int span = cdiv(cdiv(E, nwaves), SLOTS) * SLOTS;
    int base = wid * span;
    int endv = base + span;
    if (endv > E) endv = E;
    if (base >= endv) return;

    h2 wreg[8][Cin / 2];

    while (base < endv) {
        const int w0 = __builtin_amdgcn_readfirstlane(
            (int)(records[base].x >> 18));
        // unconditional per-run weight load (per-lane column o, from L2/L1)
#pragma unroll
        for (int t = 0; t < 8; ++t) {
            const _Float16* wp = Wg + (w0 + TAP[t]) * CC + o * 8;
#pragma unroll
            for (int c = 0; c < Cin / 8; ++c) {
                union { uint4 u4; unsigned u[4]; } wu;
                wu.u4 = *(const uint4*)(wp + c * (8 * Cout));
                wreg[t][4 * c + 0] = __builtin_bit_cast(h2, wu.u[0]);
                wreg[t][4 * c + 1] = __builtin_bit_cast(h2, wu.u[1]);
                wreg[t][4 * c + 2] = __builtin_bit_cast(h2, wu.u[2]);
                wreg[t][4 * c + 3] = __builtin_bit_cast(h2, wu.u[3]);
            }
        }
        int k = SLOTS;
        do {
            const int idx = base + slot;
            const bool act = idx < endv;
            uint2 rec = records[act ? idx : endv - 1];
            const unsigned wib = rec.x >> 18;
            unsigned long long neq = __ballot(act && (wib != (unsigned)w0));
            k = neq ? (int)((__ffsll((long long)neq) - 1) >> LOG2C) : SLOTS;

            float bb[8];
            unpack_bb10(rec.y, bb);
            const unsigned sn = rec.x & 0x3FFFFu;
            h2 hx[Cin / 2];
            const uint4* xp = (const uint4*)(xh + (size_t)sn * (Cin / 2));
#pragma unroll
            for (int c = 0; c < Cin / 8; ++c) {
                uint4 q = xp[c];
                hx[4 * c + 0] = __builtin_bit_cast(h2, q.x);
                hx[4 * c + 1] = __builtin_bit_cast(h2, q.y);
                hx[4 * c + 2] = __builtin_bit_cast(h2, q.z);
                hx[4 * c + 3] = __builtin_bit_cast(h2, q.w);
            }
            float acc = 0.f;
#pragma unroll
            for (int t = 0; t < 8; ++t) {
                float dot = 0.f;
#pragma unroll
                for (int kk = 0; kk < Cin / 2; ++kk)
                    dot = fdot2f(hx[kk], wreg[t][kk], dot);
                acc = fmaf(bb[t], dot, acc);
            }
            if (act && slot < k)
                y[(size_t)iperm[idx] * Cout + o] = (_Float16)acc;
            base += k;
        } while (k == SLOTS && base < endv);
    }
}

// ---------- phase B: sequential y reduce + root + ELU; writes f32 + packed f16 ----------
template<int Cin, int Cout>
__global__ void node_reduce(const int* __restrict__ rowptr,
                            const unsigned* __restrict__ yu,
                            const float* __restrict__ x,
                            const float* __restrict__ root,
                            const float* __restrict__ bias,
                            float* __restrict__ out, unsigned* __restrict__ xh,
                            int N) {
    constexpr int C2 = Cout / 2;
    int t = blockIdx.x * blockDim.x + threadIdx.x;
    int v = t / C2, o2 = t % C2;
    if (v >= N) return;
    int beg = rowptr[v], end = rowptr[v + 1];
    float a0 = 0.f, a1 = 0.f;
    for (int p = beg; p < end; ++p) {
        h2 hh = __builtin_bit_cast(h2, yu[(size_t)p * C2 + o2]);
        a0 += (float)hh[0];
        a1 += (float)hh[1];
    }
    const int o = 2 * o2;
    a0 += bias[o]; a1 += bias[o + 1];
#pragma unroll
    for (int i = 0; i < Cin; ++i) {
        float xv = x[(size_t)v * Cin + i];
        a0 = fmaf(xv, root[i * Cout + o], a0);
        a1 = fmaf(xv, root[i * Cout + o + 1], a1);
    }
    a0 = a0 > 0.f ? a0 : expm1f(a0);
    a1 = a1 > 0.f ? a1 : expm1f(a1);
    ((float2*)out)[(size_t)v * C2 + o2] = make_float2(a0, a1);
    xh[(size_t)v * C2 + o2] = pack_u32(a0, a1);
}

// ---------- fused small layers (records_d in dst-CSR order: contiguous reads) ----------

__global__ __launch_bounds__(512) void agg_l1(
        const int* __restrict__ rowptr, const uint2* __restrict__ records_d,
        const float* __restrict__ x, const float* __restrict__ W,
        const float* __restrict__ root, const float* __restrict__ bias,
        float* __restrict__ out, unsigned* __restrict__ xh2,
        int N, int totalWaves) {
    const int lane = threadIdx.x & 63;
    const int o = lane & 7;
    const int slot = lane >> 3;
    const int wid = blockIdx.x * 8 + (threadIdx.x >> 6);
    constexpr int TAP[8] = {0, 25, 5, 30, 1, 26, 6, 31};

    for (int v = wid; v < N; v += totalWaves) {
        const int beg = rowptr[v], end = rowptr[v + 1];
        float acc = 0.0f;
        for (int p0 = beg; p0 < end; p0 += 8) {
            const int p = p0 + slot;
            float xv = 0.f, bb[8];
            int wib = 0;
#pragma unroll
            for (int t = 0; t < 8; ++t) bb[t] = 0.f;
            if (p < end) {
                uint2 rec = records_d[p];
                unpack_bb10(rec.y, bb);
                wib = (int)(rec.x >> 18);
                xv = x[rec.x & 0x3FFFFu];
            }
#pragma unroll
            for (int t = 0; t < 8; ++t)
                acc = fmaf(bb[t] * xv, __ldg(&W[(wib + TAP[t]) * 8 + o]), acc);
        }
#pragma unroll
        for (int m = 8; m < 64; m <<= 1) acc += __shfl_xor(acc, m);
        if (slot == 0) {
            float z = acc + bias[o] + x[v] * root[o];
            z = z > 0.0f ? z : expm1f(z);
            out[(size_t)v * 8 + o] = z;
            float zp = __shfl_xor(z, 1);
            if ((o & 1) == 0) xh2[(size_t)v * 4 + (o >> 1)] = pack_u32(z, zp);
        }
    }
}

__global__ __launch_bounds__(512) void agg_l5(
        const int* __restrict__ rowptr, const uint2* __restrict__ records_d,
        const float* __restrict__ x, const float* __restrict__ W,
        const float* __restrict__ root, const float* __restrict__ bias,
        float* __restrict__ out, int N, int totalWaves) {
    const int lane = threadIdx.x & 63;
    const int i = lane & 7;
    const int slot = lane >> 3;
    const int wid = blockIdx.x * 8 + (threadIdx.x >> 6);
    constexpr int TAP[8] = {0, 25, 5, 30, 1, 26, 6, 31};

    for (int v = wid; v < N; v += totalWaves) {
        const int beg = rowptr[v], end = rowptr[v + 1];
        float acc = 0.0f;
        for (int p0 = beg; p0 < end; p0 += 8) {
            const int p = p0 + slot;
            float xi = 0.f, bb[8];
            int wib = 0;
#pragma unroll
            for (int t = 0; t < 8; ++t) bb[t] = 0.f;
            if (p < end) {
                uint2 rec = records_d[p];
                unpack_bb10(rec.y, bb);
                wib = (int)(rec.x >> 18);
                xi = x[(size_t)(rec.x & 0x3FFFFu) * 8 + i];
            }
#pragma unroll
            for (int t = 0; t < 8; ++t)
                acc = fmaf(bb[t] * xi, __ldg(&W[(wib + TAP[t]) * 8 + i]), acc);
        }
        if (slot == 0) acc = fmaf(x[(size_t)v * 8 + i], root[i], acc);
#pragma unroll
        for (int m = 1; m < 64; m <<= 1) acc += __shfl_xor(acc, m);
        if (lane == 0) {
            float z = acc + bias[0];
            out[v] = z > 0.0f ? z : expm1f(z);
        }
    }
}

// ---------- host ----------

static inline char* align256(char* p) {
    return (char*)(((uintptr_t)p + 255) & ~(uintptr_t)255);
}

extern "C" void kernel_launch(void* const* d_in, const int* in_sizes, int n_in,
                              void* d_out, int out_size, void* d_ws, size_t ws_size,
                              hipStream_t stream) {
    const float* x    = (const float*)d_in[0];
    const int*   ei   = (const int*)d_in[1];
    const float* attr = (const float*)d_in[2];
    const float* w[5]    = {(const float*)d_in[3],  (const float*)d_in[6],
                            (const float*)d_in[9],  (const float*)d_in[12],
                            (const float*)d_in[15]};
    const float* root[5] = {(const float*)d_in[4],  (const float*)d_in[7],
                            (const float*)d_in[10], (const float*)d_in[13],
                            (const float*)d_in[16]};
    const float* bias[5] = {(const float*)d_in[5],  (const float*)d_in[8],
                            (const float*)d_in[11], (const float*)d_in[14],
                            (const float*)d_in[17]};

    const int N = in_sizes[0];
    const int E = in_sizes[1] / 2;
    const int* src = ei;
    const int* dst = ei + E;

    char* ws = (char*)d_ws;
    float* bufA      = (float*)ws;    ws = align256(ws + (size_t)N * 16 * 4);
    float* bufB      = (float*)ws;    ws = align256(ws + (size_t)N * 16 * 4);
    int*   counts    = (int*)ws;      ws = align256(ws + (size_t)(N + 128) * 4);
    int*   bcnt      = counts + N;    // zeroed together with counts
    int*   cursor    = (int*)ws;      ws = align256(ws + (size_t)N * 4);
    int*   rowptr    = (int*)ws;      ws = align256(ws + (size_t)(N + 1) * 4);
    int*   bsums     = (int*)ws;      ws = align256(ws + 256 * 4);
    int*   bcursor   = (int*)ws;      ws = align256(ws + 128 * 4);
    uint2* records   = (uint2*)ws;    ws = align256(ws + (size_t)E * 8);
    uint2* records_d = (uint2*)ws;    ws = align256(ws + (size_t)E * 8);
    int*   iperm     = (int*)ws;      ws = align256(ws + (size_t)E * 4);
    _Float16* y      = (_Float16*)ws; ws = align256(ws + (size_t)E * 16 * 2);
    unsigned* xhA    = (unsigned*)ws; ws = align256(ws + (size_t)N * 8 * 4);
    unsigned* xhB    = (unsigned*)ws; ws = align256(ws + (size_t)N * 8 * 4);
    _Float16* wh2    = (_Float16*)ws; ws = align256(ws + (size_t)KTOT * 8 * 16 * 2);
    _Float16* wh3    = (_Float16*)ws; ws = align256(ws + (size_t)KTOT * 16 * 16 * 2);
    _Float16* wh4    = (_Float16*)ws; ws = align256(ws + (size_t)KTOT * 16 * 8 * 2);

    const int B = 256;
    const int nb = cdiv(N, 256);
    const int nchunk = cdiv(E, CHUNK);
    const int nprep = cdiv(64000, 256);
    const unsigned* yu = (const unsigned*)y;

    (void)hipMemsetAsync(counts, 0, (size_t)(N + 128) * 4, stream);
    hist_tr<<<nchunk, 256, 0, stream>>>(x, bufA, dst, attr, counts, bcnt, N, E);
    scan_blocks<<<nb, 256, 0, stream>>>(counts, rowptr, bsums, N);
    add_offsets2<<<nb, 256, 0, stream>>>(rowptr, bsums, cursor, bcnt, bcursor,
                                         nb, N, E);
    scatter_prep<<<nchunk + nprep, 256, 0, stream>>>(
        src, dst, attr, cursor, bcursor, records, records_d, iperm, E, nchunk,
        w[1], w[2], w[3], wh2, wh3, wh4);

    const int GB = 512, TW = GB * 8;

    // L1 (1->8), fused; writes f32 out + f16 xhA
    agg_l1<<<GB, 512, 0, stream>>>(rowptr, records_d, bufA, w[0],
                                   root[0], bias[0], bufB, xhA, N, TW);
    // L2 (8->16)
    edge_gemm<8, 16><<<GB, 512, 0, stream>>>(records, xhA, wh2, iperm, y, E);
    node_reduce<8, 16><<<cdiv(N * 8, B), B, 0, stream>>>(rowptr, yu, bufB,
                                                         root[1], bias[1], bufA, xhB, N);
    // L3 (16->16)
    edge_gemm<16, 16><<<GB, 512, 0, stream>>>(records, xhB, wh3, iperm, y, E);
    node_reduce<16, 16><<<cdiv(N * 8, B), B, 0, stream>>>(rowptr, yu, bufA,
                                                          root[2], bias[2], bufB, xhA, N);
    // L4 (16->8)
    edge_gemm<16, 8><<<GB, 512, 0, stream>>>(records, xhA, wh4, iperm, y, E);
    node_reduce<16, 8><<<cdiv(N * 4, B), B, 0, stream>>>(rowptr, yu, bufB,
                                                         root[3], bias[3], bufA, xhB, N);
    // L5 (8->1), fused
    agg_l5<<<GB, 512, 0, stream>>>(rowptr, records_d, bufA, w[4],
                                   root[4], bias[4], (float*)d_out, N, TW);
}